// Round 2
// baseline (65.590 us; speedup 1.0000x reference)
//
#include <hip/hip_runtime.h>
#include <math.h>

// Grayscale morphological dilation, 7x7 additive SE, zero 'same' padding:
//   out[p, i, j] = max_{a,b in 0..6} ( xz(p, i+a-3, j+b-3) + w[a,b] )
//
// Block = 256 threads -> 256-col x 28-row output tile.
// Stage input tile (34 rows x 264 cols, 35.9 KB) into LDS once (all global
// loads issued up front, single wait), then compute entirely from LDS.
// Weights forced into SGPRs via readfirstlane (VALU reads 1 SGPR free).
// Thread tile 4 wide x 7 tall, streaming accumulator over 13 LDS rows,
// fully static indexing -> registers only.

#define HH 512
#define WW 512

#define LROWS 34            // 28 + 6 halo
#define LCOLS 264           // 256 + 8 halo (16B-aligned row stride: 1056 B)
#define NCHUNK (LROWS * (LCOLS / 4))   // 34*66 = 2244 float4 chunks

__global__ __launch_bounds__(256) void dilate7(const float* __restrict__ x,
                                               const float* __restrict__ wg,
                                               float* __restrict__ out) {
  __shared__ float lds[LROWS * LCOLS];

  const int tid = threadIdx.x;
  const int lc = tid & 63;                       // 64 thread-cols per wave
  const int tr = tid >> 6;                       // wave id = thread-row
  const int col0b = blockIdx.x * 256;            // block output col base
  const int row0b = blockIdx.y * 28;             // block output row base

  const size_t plane_off = (size_t)blockIdx.z * (size_t)(HH * WW);
  const float* xp = x + plane_off;
  float* op = out + plane_off;

  // ---- Weights -> SGPRs (uniform across wave) ----
  float wv[49];
#pragma unroll
  for (int i = 0; i < 49; ++i) {
    int b = __builtin_amdgcn_readfirstlane(__float_as_int(wg[i]));
    wv[i] = __int_as_float(b);
  }

  // ---- Stage global -> LDS (zero-filled halo) ----
  // chunk idx -> (r, c4): r = idx/66, c4 = idx%66. Global src:
  // grow = row0b - 3 + r, gcol = col0b - 4 + c4*4. Chunks are 16B aligned
  // and never straddle the [0,512) boundary (gcol multiple of 4).
#pragma unroll
  for (int i = 0; i < 9; ++i) {
    int idx = tid + i * 256;
    if (idx < NCHUNK) {
      int r = idx / 66;
      int c4 = idx - r * 66;
      int grow = row0b - 3 + r;
      int gcol = col0b - 4 + c4 * 4;
      bool ok = ((unsigned)grow < (unsigned)HH) && ((unsigned)gcol < (unsigned)WW);
      float4 v = make_float4(0.f, 0.f, 0.f, 0.f);
      if (ok) v = *reinterpret_cast<const float4*>(xp + (size_t)grow * WW + gcol);
      *reinterpret_cast<float4*>(&lds[r * LCOLS + c4 * 4]) = v;
    }
  }
  __syncthreads();

  // ---- Compute from LDS ----
  float acc[7][4];
#pragma unroll
  for (int t = 0; t < 7; ++t)
#pragma unroll
    for (int j = 0; j < 4; ++j) acc[t][j] = -INFINITY;

#pragma unroll
  for (int k = 0; k < 13; ++k) {
    // LDS row (tr*7 + k) holds global row (row0b - 3 + tr*7 + k).
    const float* lrow = &lds[(tr * 7 + k) * LCOLS + lc * 4];
    float4 v0 = *reinterpret_cast<const float4*>(lrow);      // cols col0-4..col0-1
    float4 v1 = *reinterpret_cast<const float4*>(lrow + 4);  // cols col0  ..col0+3
    float4 v2 = *reinterpret_cast<const float4*>(lrow + 8);  // cols col0+4..col0+7
    const float rv[12] = {v0.x, v0.y, v0.z, v0.w,
                          v1.x, v1.y, v1.z, v1.w,
                          v2.x, v2.y, v2.z, v2.w};

    const int tlo = (k > 6) ? (k - 6) : 0;
    const int thi = (k < 6) ? k : 6;
#pragma unroll
    for (int t = 0; t < 7; ++t) {
      if (t < tlo || t > thi) continue;          // folds away at compile time
      const int a = k - t;                       // SE row feeding out-row t
#pragma unroll
      for (int j = 0; j < 4; ++j) {
        // tap b: input col (col0+j+b-3) -> rv[j + 1 + b]
        float m = acc[t][j];
        float c0 = rv[j + 1] + wv[a * 7 + 0];
        float c1 = rv[j + 2] + wv[a * 7 + 1];
        m = fmaxf(m, fmaxf(c0, c1));             // v_max3_f32
        float c2 = rv[j + 3] + wv[a * 7 + 2];
        float c3 = rv[j + 4] + wv[a * 7 + 3];
        m = fmaxf(m, fmaxf(c2, c3));
        float c4 = rv[j + 5] + wv[a * 7 + 4];
        float c5 = rv[j + 6] + wv[a * 7 + 5];
        m = fmaxf(m, fmaxf(c4, c5));
        float c6 = rv[j + 7] + wv[a * 7 + 6];
        m = fmaxf(m, c6);
        acc[t][j] = m;
      }
    }
  }

  // ---- Store ----
  const int col0 = col0b + lc * 4;
  const int row0 = row0b + tr * 7;
#pragma unroll
  for (int t = 0; t < 7; ++t) {
    const int rr = row0 + t;
    if (rr < HH) {
      float4 o = make_float4(acc[t][0], acc[t][1], acc[t][2], acc[t][3]);
      *reinterpret_cast<float4*>(op + (size_t)rr * WW + col0) = o;
    }
  }
}

extern "C" void kernel_launch(void* const* d_in, const int* in_sizes, int n_in,
                              void* d_out, int out_size, void* d_ws, size_t ws_size,
                              hipStream_t stream) {
  const float* x = (const float*)d_in[0];
  const float* w = (const float*)d_in[1];
  float* out = (float*)d_out;
  const int planes = in_sizes[0] / (HH * WW);    // 8*8 = 64
  dim3 grid(2, 19, planes);                      // cols: 2*256, rows: 19*28 >= 512
  dilate7<<<grid, dim3(256, 1, 1), 0, stream>>>(x, w, out);
}